// Round 7
// baseline (141.434 us; speedup 1.0000x reference)
//
#include <hip/hip_runtime.h>

#define EPS 1e-6f

typedef unsigned short u16;
typedef u16   u16x4  __attribute__((ext_vector_type(4)));
typedef u16   u16x8  __attribute__((ext_vector_type(8)));
typedef float f32x4  __attribute__((ext_vector_type(4)));
typedef _Float16 f16x8 __attribute__((ext_vector_type(8)));

// ---------------- helpers ----------------
__device__ __forceinline__ u16 f2h(float f) { return __builtin_bit_cast(u16, (_Float16)f); }

__device__ __forceinline__ f16x8 lds_f16x8(const u16* p) {
  u16x8 r = *(const u16x8*)p;
  return __builtin_bit_cast(f16x8, r);
}

__device__ __forceinline__ f32x4 mfma16(f16x8 a, f16x8 b, f32x4 c) {
  return __builtin_amdgcn_mfma_f32_16x16x32_f16(a, b, c, 0, 0, 0);
}

__device__ __forceinline__ float r_poly_f(float a) {
  float d  = 0.5f - a;
  float d2 = d * d;
  float num = 0.25f + 1.65811f * d + 2.15388f * d2 + 8.2844f * d2 * d + 6.16764f * d2 * d2;
  float den = a * (1.0f - a);
  if (fabsf(den) < EPS) den = EPS;
  return num / den;
}

// Branchless combine step. Per-node params p[16] (uniform across lanes -> s_load):
// p0=w0 p1=w1 p2=a_fb p3=flip p4=s_lin p5=s_mn p6=s_xy p7=s_pm
// p8=s_pow p9=s_r0 p10=r_sel p11=rinv_sel p12=c0pow
// All 6 terms always computed, guaranteed finite; weights select.
__device__ __forceinline__ float combine_bl(float carry, float leaf, const float* __restrict__ p) {
  float w0 = p[0], w1 = p[1], a_fb = p[2];
  bool flip = p[3] > 0.5f;
  float s_lin = p[4], s_mn = p[5], s_xy = p[6], s_pm = p[7];
  float s_pow = p[8], s_r0 = p[9], rs = p[10], rinv = p[11], c0p = p[12];

  float xx = __builtin_isnan(carry) ? EPS : carry;
  float yy = __builtin_isnan(leaf)  ? EPS : leaf;
  xx = fminf(fmaxf(xx, EPS), 1.0f - EPS);
  yy = fminf(fmaxf(yy, EPS), 1.0f - EPS);
  float X = flip ? (1.0f - xx) : xx;
  float Y = flip ? (1.0f - yy) : yy;

  float lx = log2f(X), ly = log2f(Y);
  float tx = exp2f(rs * lx), ty = exp2f(rs * ly);
  float s  = w0 * tx + w1 * ty;
  float pm = exp2f(rinv * log2f(s));
  float lin = w0 * X + w1 * Y;
  float mn  = fminf(X, Y);
  float xy  = X * Y;
  float pw  = exp2f(c0p * (lx + ly));
  float r0  = (fabsf(X - 1.0f) < EPS && fabsf(Y - 1.0f) < EPS) ? 1.0f : 0.0f;

  float r = s_lin * lin + s_mn * mn + s_xy * xy + s_pm * pm + s_pow * pw + s_r0 * r0;
  if (flip) r = 1.0f - r;
  if (__builtin_isnan(r)) r = a_fb;
  return r;
}

// ---------------- kernel 1: per-node branchless chain params ----------------
__global__ void param_kernel(const float* __restrict__ W, const float* __restrict__ Bv,
                             float* __restrict__ prm, int n) {
  int i = blockIdx.x * blockDim.x + threadIdx.x;
  if (i >= n) return;
  float w0r = W[2 * i], w1r = W[2 * i + 1];
  float m  = fmaxf(w0r, w1r);
  float e0 = expf(w0r - m), e1 = expf(w1r - m);
  float inv = 1.0f / (e0 + e1);
  float w0 = e0 * inv, w1 = e1 * inv;

  float b   = Bv[i];
  float sig = 1.0f / (1.0f + expf(-b));
  float a_fb = sig * 3.0f - 1.0f;

  float a = a_fb;
  if (__builtin_isnan(a)) a = -1.0f;
  a = fminf(fmaxf(a, -1.0f + EPS), 2.0f - EPS);
  int flip = (a < 0.5f - EPS) ? 1 : 0;
  float aa = a;
  if (flip) aa = fminf(fmaxf(1.0f - a, -1.0f + EPS), 2.0f - EPS);

  // weights for the branchless sum (priority: R0 > R1 > XY > R3 > MIN > R5 > R6 > LIN)
  float s_lin = 0.f, s_mn = 0.f, s_xy = 0.f, s_pm = 0.f, s_pow = 0.f, s_r0 = 0.f;
  float rs = 1.0f, rinv = 1.0f, c0p = 0.0f;     // benign defaults keep terms finite

  if (fabsf(aa - 2.0f) < EPS) {
    s_r0 = 1.0f;
  } else if (aa > 1.25f && aa < 2.0f) {
    s_pow = 1.0f;
    c0p = sqrtf(fmaxf(3.0f / fmaxf(2.0f - aa, EPS) - 1.0f, EPS));
  } else if (fabsf(aa - 1.25f) < EPS) {
    s_xy = 1.0f;
  } else if (aa > 1.0f && aa < 1.25f) {
    s_mn = 4.0f * (1.25f - aa); s_xy = 4.0f * (aa - 1.0f);
  } else if (fabsf(aa - 1.0f) < EPS) {
    s_mn = 1.0f;
  } else if (aa >= 0.75f && aa < 1.0f) {
    float ac = fminf(fmaxf(aa, 0.75f), 1.0f - EPS);
    float ra = r_poly_f(ac);
    if (fabsf(ra) < EPS) ra = EPS;
    s_pm = 1.0f; rs = ra; rinv = 1.0f / ra;
  } else if (aa > 0.5f && aa < 0.75f) {
    float R = r_poly_f(0.75f);
    if (fabsf(R) < EPS) R = EPS;
    s_lin = 3.0f - 4.0f * aa; s_pm = 4.0f * aa - 2.0f; rs = R; rinv = 1.0f / R;
  } else {
    s_lin = 1.0f;
  }

  float* o = prm + i * 16;
  o[0] = w0;  o[1] = w1;  o[2] = a_fb; o[3] = (float)flip;
  o[4] = s_lin; o[5] = s_mn; o[6] = s_xy; o[7] = s_pm;
  o[8] = s_pow; o[9] = s_r0; o[10] = rs; o[11] = rinv; o[12] = c0p;
  o[13] = 0.f; o[14] = 0.f; o[15] = 0.f;
}

// ---------------- kernel 2: register-resident Sinkhorn (fp16 PT out) ----------------
__global__ __launch_bounds__(1024, 4) void sinkhorn_kernel(
    const float* __restrict__ logits, u16* __restrict__ PTf) {
  __shared__ float alpha[256], beta[256];
  __shared__ float psum[256][33];

  const int t  = threadIdx.x;
  const int R  = t >> 5;
  const int C  = t & 31;
  const int r0 = R << 3;

  float e[8][8];
  #pragma unroll
  for (int dr = 0; dr < 8; ++dr) {
    const float* row = logits + (r0 + dr) * 256 + C;
    #pragma unroll
    for (int m = 0; m < 8; ++m) e[dr][m] = __expf(row[m << 5]);
  }

  if (t < 256) beta[t] = 1.0f;
  __syncthreads();

  for (int it = 0; it < 10; ++it) {
    {
      float bv[8], acc[8];
      #pragma unroll
      for (int m = 0; m < 8; ++m) bv[m] = beta[C + (m << 5)];
      #pragma unroll
      for (int dr = 0; dr < 8; ++dr) {
        float s = 0.f;
        #pragma unroll
        for (int m = 0; m < 8; ++m) s += e[dr][m] * bv[m];
        acc[dr] = s;
      }
      #pragma unroll
      for (int dr = 0; dr < 8; ++dr) psum[r0 + dr][C] = acc[dr];
    }
    __syncthreads();
    if (t < 256) {
      float s = 0.f;
      #pragma unroll
      for (int j = 0; j < 32; ++j) s += psum[t][j];
      alpha[t] = 1.0f / s;
    }
    __syncthreads();
    {
      float av[8], acc[8];
      #pragma unroll
      for (int dr = 0; dr < 8; ++dr) av[dr] = alpha[r0 + dr];
      #pragma unroll
      for (int m = 0; m < 8; ++m) {
        float s = 0.f;
        #pragma unroll
        for (int dr = 0; dr < 8; ++dr) s += e[dr][m] * av[dr];
        acc[m] = s;
      }
      #pragma unroll
      for (int m = 0; m < 8; ++m) psum[C + (m << 5)][R] = acc[m];
    }
    __syncthreads();
    if (t < 256) {
      float s = 0.f;
      #pragma unroll
      for (int j = 0; j < 32; ++j) s += psum[t][j];
      beta[t] = 1.0f / s;
    }
    __syncthreads();
  }

  float av[8], bv[8];
  #pragma unroll
  for (int dr = 0; dr < 8; ++dr) av[dr] = alpha[r0 + dr];
  #pragma unroll
  for (int m = 0; m < 8; ++m) bv[m] = beta[C + (m << 5)];

  #pragma unroll
  for (int m = 0; m < 8; ++m) {
    int l = C + (m << 5);
    u16x8 vh;
    #pragma unroll
    for (int dr = 0; dr < 8; ++dr) vh[dr] = f2h(av[dr] * e[dr][m] * bv[m]);
    *(u16x8*)(PTf + l * 256 + r0) = vh;
  }
}

// ---------------- kernel 3: fused fp16 single-pass MFMA GEMM + branchless chain ----------------
// GEMM section identical to round 6 (101 us baseline): 512 thr, 2M x 4N waves,
// b-tile 128, K-step 32, XOR group-swizzled LDS (0 bank conflicts).
// Chain: branchless combine, params via uniform global loads (s_load broadcast).
#define CSTR 132

__global__ __launch_bounds__(512, 4) void gemm_chain_kernel(
    const float* __restrict__ x, const u16* __restrict__ PTf,
    const float* __restrict__ prm, float* __restrict__ out) {
  __shared__ __align__(16) char smem[33792];
  u16* xs = (u16*)smem;                      // [128][32] fp16 (swizzled groups)
  u16* pt = (u16*)(smem + 8192);             // [256][32] fp16 (swizzled groups)
  float* cbuf = (float*)smem;                // [64][CSTR] epilogue alias

  const int t    = threadIdx.x;
  const int w    = t >> 6;
  const int lane = t & 63;
  const int bl   = lane & 15;
  const int kh   = lane >> 4;
  const int wm   = w >> 2;                   // 0..1
  const int wn   = w & 3;                    // 0..3
  const int b0   = blockIdx.x * 128;

  const int xrow = t >> 3;                   // 0..63 (rows xrow, xrow+64)
  const int xc4  = t & 7;                    // f32x4 slot in 32-float slice

  f32x4 acc[8][2];
  #pragma unroll
  for (int m = 0; m < 8; ++m) {
    acc[m][0] = f32x4{0.f, 0.f, 0.f, 0.f};
    acc[m][1] = f32x4{0.f, 0.f, 0.f, 0.f};
  }

  f32x4 xr[2];
  u16x8 pr[2];

  // ---- prologue: prefetch tile 0 (PT with pre-swizzled source) ----
  #pragma unroll
  for (int j = 0; j < 2; ++j) {
    xr[j] = *(const f32x4*)(x + (b0 + xrow + 64 * j) * 256 + (xc4 << 2));
    int c = t + 512 * j, r = c >> 2, s = c & 3, g = s ^ ((r >> 1) & 3);
    pr[j] = *(const u16x8*)(PTf + r * 256 + (g << 3));
  }

  for (int kc = 0; kc < 8; ++kc) {
    // ---- W phase ----
    #pragma unroll
    for (int j = 0; j < 2; ++j) {
      int row = xrow + 64 * j;
      u16x4 hv;
      #pragma unroll
      for (int e = 0; e < 4; ++e) hv[e] = f2h(xr[j][e]);
      int g = xc4 >> 1, sub = xc4 & 1;
      *(u16x4*)(xs + row * 32 + ((g ^ ((row >> 1) & 3)) << 3) + (sub << 2)) = hv;
      *(u16x8*)(pt + ((t + 512 * j) << 3)) = pr[j];   // linear (content pre-swizzled)
    }
    __syncthreads();

    // ---- prefetch next tile (lands under C phase) ----
    if (kc < 7) {
      int k1 = (kc + 1) << 5;
      #pragma unroll
      for (int j = 0; j < 2; ++j) {
        xr[j] = *(const f32x4*)(x + (b0 + xrow + 64 * j) * 256 + k1 + (xc4 << 2));
        int c = t + 512 * j, r = c >> 2, s = c & 3, g = s ^ ((r >> 1) & 3);
        pr[j] = *(const u16x8*)(PTf + r * 256 + k1 + (g << 3));
      }
    }

    // ---- C phase ----
    f16x8 bh[2];
    #pragma unroll
    for (int nf = 0; nf < 2; ++nf) {
      int brow = (wn << 5) + (nf << 4) + bl;
      bh[nf] = lds_f16x8(xs + brow * 32 + ((kh ^ ((brow >> 1) & 3)) << 3));
    }
    #pragma unroll
    for (int mf = 0; mf < 8; ++mf) {
      int arow = (wm << 7) + (mf << 4) + bl;
      f16x8 ah = lds_f16x8(pt + arow * 32 + ((kh ^ ((arow >> 1) & 3)) << 3));
      #pragma unroll
      for (int nf = 0; nf < 2; ++nf)
        acc[mf][nf] = mfma16(ah, bh[nf], acc[mf][nf]);
    }
    __syncthreads();
  }

  float carry = 0.0f;

  #pragma unroll
  for (int c = 0; c < 4; ++c) {
    __syncthreads();
    // waves with wm == c>>1 dump l-chunk [64c, 64c+64) into cbuf[l'][b]
    if (wm == (c >> 1)) {
      #pragma unroll
      for (int d = 0; d < 4; ++d) {
        int mf = ((c & 1) << 2) + d;
        #pragma unroll
        for (int nf = 0; nf < 2; ++nf) {
          int bc = (wn << 5) + (nf << 4) + bl;
          #pragma unroll
          for (int r = 0; r < 4; ++r) {
            int lr = (d << 4) + (kh << 2) + r;
            cbuf[lr * CSTR + bc] = acc[mf][nf][r];
          }
        }
      }
    }
    __syncthreads();
    if (t < 128) {
      for (int lc = 0; lc < 64; lc += 4) {
        float v[4];
        #pragma unroll
        for (int u = 0; u < 4; ++u) v[u] = cbuf[(lc + u) * CSTR + t];
        #pragma unroll
        for (int u = 0; u < 4; ++u) {
          int l = (c << 6) + lc + u;
          carry = (l == 0) ? v[u] : combine_bl(carry, v[u], prm + ((l - 1) << 4));
        }
      }
    }
  }
  if (t < 128) out[b0 + t] = carry;
}

// ---------------- launch ----------------
extern "C" void kernel_launch(void* const* d_in, const int* in_sizes, int n_in,
                              void* d_out, int out_size, void* d_ws, size_t ws_size,
                              hipStream_t stream) {
  const float* x       = (const float*)d_in[0];   // (65536, 256)
  const float* logits  = (const float*)d_in[1];   // (256, 256)
  const float* weights = (const float*)d_in[2];   // (255, 2)
  const float* biases  = (const float*)d_in[3];   // (255,)
  float* out = (float*)d_out;                     // (65536, 1)

  char* ws = (char*)d_ws;
  u16*   PTf = (u16*)ws;                          // 131072 B (fp16 P^T)
  float* prm = (float*)(ws + 131072);             // 255*16*4 = 16320 B

  int Btot = in_sizes[0] / 256;                   // 65536

  param_kernel<<<1, 256, 0, stream>>>(weights, biases, prm, 255);
  sinkhorn_kernel<<<1, 1024, 0, stream>>>(logits, PTf);
  gemm_chain_kernel<<<Btot / 128, 512, 0, stream>>>(x, PTf, prm, out);
}

// Round 8
// 133.508 us; speedup vs baseline: 1.0594x; 1.0594x over previous
//
#include <hip/hip_runtime.h>

#define EPS 1e-6f

typedef unsigned short u16;
typedef u16   u16x4  __attribute__((ext_vector_type(4)));
typedef u16   u16x8  __attribute__((ext_vector_type(8)));
typedef float f32x4  __attribute__((ext_vector_type(4)));
typedef _Float16 f16x8 __attribute__((ext_vector_type(8)));

enum { BR_LIN = 0, BR_R6, BR_R5, BR_MIN, BR_R3, BR_XY, BR_R1, BR_R0 };

// ---------------- helpers ----------------
__device__ __forceinline__ u16 f2h(float f) { return __builtin_bit_cast(u16, (_Float16)f); }

__device__ __forceinline__ f16x8 lds_f16x8(const u16* p) {
  u16x8 r = *(const u16x8*)p;
  return __builtin_bit_cast(f16x8, r);
}

__device__ __forceinline__ f32x4 mfma16(f16x8 a, f16x8 b, f32x4 c) {
  return __builtin_amdgcn_mfma_f32_16x16x32_f16(a, b, c, 0, 0, 0);
}

__device__ __forceinline__ float r_poly_f(float a) {
  float d  = 0.5f - a;
  float d2 = d * d;
  float num = 0.25f + 1.65811f * d + 2.15388f * d2 + 8.2844f * d2 * d + 6.16764f * d2 * d2;
  float den = a * (1.0f - a);
  if (fabsf(den) < EPS) den = EPS;
  return num / den;
}

__device__ __forceinline__ float pmean(float X, float Y, float r, float rinv, float w0, float w1) {
  float tx = exp2f(r * log2f(X));
  float ty = exp2f(r * log2f(Y));
  float s  = w0 * tx + w1 * ty;
  return exp2f(rinv * log2f(s));
}

// branchy combine step; p[8] per node; branch is wave-uniform (all lanes same node)
__device__ __forceinline__ float combine_step(float carry, float leaf, const float* p) {
  float w0 = p[0], w1 = p[1], a_fb = p[2];
  float c0 = p[3], c1 = p[4], c2 = p[5], c3 = p[6];
  int meta = __float_as_int(p[7]);
  int br = meta & 0xff, flip = meta >> 8;

  float xx = carry, yy = leaf;
  xx = __builtin_isnan(xx) ? EPS : xx;
  yy = __builtin_isnan(yy) ? EPS : yy;
  xx = fminf(fmaxf(xx, EPS), 1.0f - EPS);
  yy = fminf(fmaxf(yy, EPS), 1.0f - EPS);
  float X = flip ? (1.0f - xx) : xx;
  float Y = flip ? (1.0f - yy) : yy;

  float r;
  switch (br) {
    default:
    case BR_LIN: r = w0 * X + w1 * Y; break;
    case BR_R6:  r = c0 * (w0 * X + w1 * Y) + c1 * pmean(X, Y, c2, c3, w0, w1); break;
    case BR_R5:  r = pmean(X, Y, c0, c1, w0, w1); break;
    case BR_MIN: r = fminf(X, Y); break;
    case BR_R3:  r = 4.0f * (c0 * fminf(X, Y) + c1 * (X * Y)); break;
    case BR_XY:  r = X * Y; break;
    case BR_R1:  r = exp2f(c0 * log2f(X * Y)); break;
    case BR_R0:  r = (fabsf(X - 1.0f) < EPS && fabsf(Y - 1.0f) < EPS) ? 1.0f : 0.0f; break;
  }
  if (flip) r = 1.0f - r;
  if (__builtin_isnan(r)) r = a_fb;
  return r;
}

// ---------------- kernel 1: per-node chain params (8 floats) ----------------
__global__ void param_kernel(const float* __restrict__ W, const float* __restrict__ Bv,
                             float* __restrict__ prm, int n) {
  int i = blockIdx.x * blockDim.x + threadIdx.x;
  if (i >= n) return;
  float w0r = W[2 * i], w1r = W[2 * i + 1];
  float m  = fmaxf(w0r, w1r);
  float e0 = expf(w0r - m), e1 = expf(w1r - m);
  float inv = 1.0f / (e0 + e1);
  float w0 = e0 * inv, w1 = e1 * inv;

  float b   = Bv[i];
  float sig = 1.0f / (1.0f + expf(-b));
  float a_fb = sig * 3.0f - 1.0f;

  float a = a_fb;
  if (__builtin_isnan(a)) a = -1.0f;
  a = fminf(fmaxf(a, -1.0f + EPS), 2.0f - EPS);
  int flip = (a < 0.5f - EPS) ? 1 : 0;
  float aa = a;
  if (flip) aa = fminf(fmaxf(1.0f - a, -1.0f + EPS), 2.0f - EPS);

  int br; float c0 = 0.f, c1 = 0.f, c2 = 0.f, c3 = 0.f;
  if (fabsf(aa - 2.0f) < EPS) br = BR_R0;
  else if (aa > 1.25f && aa < 2.0f) {
    br = BR_R1;
    c0 = sqrtf(fmaxf(3.0f / fmaxf(2.0f - aa, EPS) - 1.0f, EPS));
  } else if (fabsf(aa - 1.25f) < EPS) br = BR_XY;
  else if (aa > 1.0f && aa < 1.25f) { br = BR_R3; c0 = 1.25f - aa; c1 = aa - 1.0f; }
  else if (fabsf(aa - 1.0f) < EPS) br = BR_MIN;
  else if (aa >= 0.75f && aa < 1.0f) {
    br = BR_R5;
    float ac = fminf(fmaxf(aa, 0.75f), 1.0f - EPS);
    float ra = r_poly_f(ac);
    if (fabsf(ra) < EPS) ra = EPS;
    c0 = ra; c1 = 1.0f / ra;
  } else if (aa > 0.5f && aa < 0.75f) {
    br = BR_R6;
    c0 = 3.0f - 4.0f * aa; c1 = 4.0f * aa - 2.0f;
    float R = r_poly_f(0.75f);
    if (fabsf(R) < EPS) R = EPS;
    c2 = R; c3 = 1.0f / R;
  } else br = BR_LIN;

  float* o = prm + i * 8;
  o[0] = w0; o[1] = w1; o[2] = a_fb; o[3] = c0; o[4] = c1; o[5] = c2; o[6] = c3;
  o[7] = __int_as_float(br | (flip << 8));
}

// ---------------- kernel 2: register-resident Sinkhorn (fp16 PT out) ----------------
__global__ __launch_bounds__(1024, 4) void sinkhorn_kernel(
    const float* __restrict__ logits, u16* __restrict__ PTf) {
  __shared__ float alpha[256], beta[256];
  __shared__ float psum[256][33];

  const int t  = threadIdx.x;
  const int R  = t >> 5;
  const int C  = t & 31;
  const int r0 = R << 3;

  float e[8][8];
  #pragma unroll
  for (int dr = 0; dr < 8; ++dr) {
    const float* row = logits + (r0 + dr) * 256 + C;
    #pragma unroll
    for (int m = 0; m < 8; ++m) e[dr][m] = __expf(row[m << 5]);
  }

  if (t < 256) beta[t] = 1.0f;
  __syncthreads();

  for (int it = 0; it < 10; ++it) {
    {
      float bv[8], acc[8];
      #pragma unroll
      for (int m = 0; m < 8; ++m) bv[m] = beta[C + (m << 5)];
      #pragma unroll
      for (int dr = 0; dr < 8; ++dr) {
        float s = 0.f;
        #pragma unroll
        for (int m = 0; m < 8; ++m) s += e[dr][m] * bv[m];
        acc[dr] = s;
      }
      #pragma unroll
      for (int dr = 0; dr < 8; ++dr) psum[r0 + dr][C] = acc[dr];
    }
    __syncthreads();
    if (t < 256) {
      float s = 0.f;
      #pragma unroll
      for (int j = 0; j < 32; ++j) s += psum[t][j];
      alpha[t] = 1.0f / s;
    }
    __syncthreads();
    {
      float av[8], acc[8];
      #pragma unroll
      for (int dr = 0; dr < 8; ++dr) av[dr] = alpha[r0 + dr];
      #pragma unroll
      for (int m = 0; m < 8; ++m) {
        float s = 0.f;
        #pragma unroll
        for (int dr = 0; dr < 8; ++dr) s += e[dr][m] * av[dr];
        acc[m] = s;
      }
      #pragma unroll
      for (int m = 0; m < 8; ++m) psum[C + (m << 5)][R] = acc[m];
    }
    __syncthreads();
    if (t < 256) {
      float s = 0.f;
      #pragma unroll
      for (int j = 0; j < 32; ++j) s += psum[t][j];
      beta[t] = 1.0f / s;
    }
    __syncthreads();
  }

  float av[8], bv[8];
  #pragma unroll
  for (int dr = 0; dr < 8; ++dr) av[dr] = alpha[r0 + dr];
  #pragma unroll
  for (int m = 0; m < 8; ++m) bv[m] = beta[C + (m << 5)];

  #pragma unroll
  for (int m = 0; m < 8; ++m) {
    int l = C + (m << 5);
    u16x8 vh;
    #pragma unroll
    for (int dr = 0; dr < 8; ++dr) vh[dr] = f2h(av[dr] * e[dr][m] * bv[m]);
    *(u16x8*)(PTf + l * 256 + r0) = vh;
  }
}

// ---------------- GEMM core macro-free shared code ----------------
// 512 thr = 8 waves (2M x 4N), b-tile 128, K-step 32, XOR group-swizzled LDS.

// kernel 3a: GEMM -> global C[l][b] (split path)
__global__ __launch_bounds__(512, 4) void gemm_store_kernel(
    const float* __restrict__ x, const u16* __restrict__ PTf,
    float* __restrict__ C, int B) {
  __shared__ __align__(16) char smem[24576];
  u16* xs = (u16*)smem;                      // [128][32] fp16 (swizzled groups)
  u16* pt = (u16*)(smem + 8192);             // [256][32] fp16 (swizzled groups)

  const int t    = threadIdx.x;
  const int w    = t >> 6;
  const int lane = t & 63;
  const int bl   = lane & 15;
  const int kh   = lane >> 4;
  const int wm   = w >> 2;                   // 0..1
  const int wn   = w & 3;                    // 0..3
  const int b0   = blockIdx.x * 128;

  const int xrow = t >> 3;
  const int xc4  = t & 7;

  f32x4 acc[8][2];
  #pragma unroll
  for (int m = 0; m < 8; ++m) {
    acc[m][0] = f32x4{0.f, 0.f, 0.f, 0.f};
    acc[m][1] = f32x4{0.f, 0.f, 0.f, 0.f};
  }

  f32x4 xr[2];
  u16x8 pr[2];

  #pragma unroll
  for (int j = 0; j < 2; ++j) {
    xr[j] = *(const f32x4*)(x + (b0 + xrow + 64 * j) * 256 + (xc4 << 2));
    int c = t + 512 * j, r = c >> 2, s = c & 3, g = s ^ ((r >> 1) & 3);
    pr[j] = *(const u16x8*)(PTf + r * 256 + (g << 3));
  }

  for (int kc = 0; kc < 8; ++kc) {
    #pragma unroll
    for (int j = 0; j < 2; ++j) {
      int row = xrow + 64 * j;
      u16x4 hv;
      #pragma unroll
      for (int e = 0; e < 4; ++e) hv[e] = f2h(xr[j][e]);
      int g = xc4 >> 1, sub = xc4 & 1;
      *(u16x4*)(xs + row * 32 + ((g ^ ((row >> 1) & 3)) << 3) + (sub << 2)) = hv;
      *(u16x8*)(pt + ((t + 512 * j) << 3)) = pr[j];
    }
    __syncthreads();

    if (kc < 7) {
      int k1 = (kc + 1) << 5;
      #pragma unroll
      for (int j = 0; j < 2; ++j) {
        xr[j] = *(const f32x4*)(x + (b0 + xrow + 64 * j) * 256 + k1 + (xc4 << 2));
        int c = t + 512 * j, r = c >> 2, s = c & 3, g = s ^ ((r >> 1) & 3);
        pr[j] = *(const u16x8*)(PTf + r * 256 + k1 + (g << 3));
      }
    }

    f16x8 bh[2];
    #pragma unroll
    for (int nf = 0; nf < 2; ++nf) {
      int brow = (wn << 5) + (nf << 4) + bl;
      bh[nf] = lds_f16x8(xs + brow * 32 + ((kh ^ ((brow >> 1) & 3)) << 3));
    }
    #pragma unroll
    for (int mf = 0; mf < 8; ++mf) {
      int arow = (wm << 7) + (mf << 4) + bl;
      f16x8 ah = lds_f16x8(pt + arow * 32 + ((kh ^ ((arow >> 1) & 3)) << 3));
      #pragma unroll
      for (int nf = 0; nf < 2; ++nf)
        acc[mf][nf] = mfma16(ah, bh[nf], acc[mf][nf]);
    }
    __syncthreads();
  }

  // direct scatter store: C[l][b], quarter-wave writes 64B contiguous
  #pragma unroll
  for (int mf = 0; mf < 8; ++mf) {
    #pragma unroll
    for (int nf = 0; nf < 2; ++nf) {
      int bb = b0 + (wn << 5) + (nf << 4) + bl;
      #pragma unroll
      for (int r = 0; r < 4; ++r) {
        int l = (wm << 7) + (mf << 4) + (kh << 2) + r;
        C[(size_t)l * B + bb] = acc[mf][nf][r];
      }
    }
  }
}

// kernel 3b: massively-parallel chain (one thread per batch element)
__global__ __launch_bounds__(256) void chain_kernel(
    const float* __restrict__ C, const float* __restrict__ prm,
    float* __restrict__ out, int B) {
  __shared__ float cprm[2040];
  for (int j = threadIdx.x; j < 2040; j += 256) cprm[j] = prm[j];
  __syncthreads();

  int b = blockIdx.x * 256 + threadIdx.x;
  if (b >= B) return;

  float carry = C[b];
  // 255 steps: leaf l = 1..255, node l-1. Batch leaf loads 4-wide.
  int l = 1;
  for (; l + 3 < 256; l += 4) {
    float v0 = C[(size_t)(l + 0) * B + b];
    float v1 = C[(size_t)(l + 1) * B + b];
    float v2 = C[(size_t)(l + 2) * B + b];
    float v3 = C[(size_t)(l + 3) * B + b];
    carry = combine_step(carry, v0, cprm + ((l - 1) << 3));
    carry = combine_step(carry, v1, cprm + ((l + 0) << 3));
    carry = combine_step(carry, v2, cprm + ((l + 1) << 3));
    carry = combine_step(carry, v3, cprm + ((l + 2) << 3));
  }
  for (; l < 256; ++l)
    carry = combine_step(carry, C[(size_t)l * B + b], cprm + ((l - 1) << 3));

  out[b] = carry;
}

// ---------------- kernel 3 (fallback): fused GEMM + chain (round-6, 101us) ----------------
#define CSTR 132

__global__ __launch_bounds__(512, 4) void gemm_chain_kernel(
    const float* __restrict__ x, const u16* __restrict__ PTf,
    const float* __restrict__ prm, float* __restrict__ out) {
  __shared__ __align__(16) char smem[41984];
  u16* xs = (u16*)smem;
  u16* pt = (u16*)(smem + 8192);
  float* cbuf = (float*)smem;
  float* cprm = (float*)(smem + 33792);

  const int t    = threadIdx.x;
  const int w    = t >> 6;
  const int lane = t & 63;
  const int bl   = lane & 15;
  const int kh   = lane >> 4;
  const int wm   = w >> 2;
  const int wn   = w & 3;
  const int b0   = blockIdx.x * 128;

  const int xrow = t >> 3;
  const int xc4  = t & 7;

  f32x4 acc[8][2];
  #pragma unroll
  for (int m = 0; m < 8; ++m) {
    acc[m][0] = f32x4{0.f, 0.f, 0.f, 0.f};
    acc[m][1] = f32x4{0.f, 0.f, 0.f, 0.f};
  }

  f32x4 xr[2];
  u16x8 pr[2];

  #pragma unroll
  for (int j = 0; j < 2; ++j) {
    xr[j] = *(const f32x4*)(x + (b0 + xrow + 64 * j) * 256 + (xc4 << 2));
    int c = t + 512 * j, r = c >> 2, s = c & 3, g = s ^ ((r >> 1) & 3);
    pr[j] = *(const u16x8*)(PTf + r * 256 + (g << 3));
  }

  for (int kc = 0; kc < 8; ++kc) {
    #pragma unroll
    for (int j = 0; j < 2; ++j) {
      int row = xrow + 64 * j;
      u16x4 hv;
      #pragma unroll
      for (int e = 0; e < 4; ++e) hv[e] = f2h(xr[j][e]);
      int g = xc4 >> 1, sub = xc4 & 1;
      *(u16x4*)(xs + row * 32 + ((g ^ ((row >> 1) & 3)) << 3) + (sub << 2)) = hv;
      *(u16x8*)(pt + ((t + 512 * j) << 3)) = pr[j];
    }
    __syncthreads();

    if (kc < 7) {
      int k1 = (kc + 1) << 5;
      #pragma unroll
      for (int j = 0; j < 2; ++j) {
        xr[j] = *(const f32x4*)(x + (b0 + xrow + 64 * j) * 256 + k1 + (xc4 << 2));
        int c = t + 512 * j, r = c >> 2, s = c & 3, g = s ^ ((r >> 1) & 3);
        pr[j] = *(const u16x8*)(PTf + r * 256 + k1 + (g << 3));
      }
    }

    f16x8 bh[2];
    #pragma unroll
    for (int nf = 0; nf < 2; ++nf) {
      int brow = (wn << 5) + (nf << 4) + bl;
      bh[nf] = lds_f16x8(xs + brow * 32 + ((kh ^ ((brow >> 1) & 3)) << 3));
    }
    #pragma unroll
    for (int mf = 0; mf < 8; ++mf) {
      int arow = (wm << 7) + (mf << 4) + bl;
      f16x8 ah = lds_f16x8(pt + arow * 32 + ((kh ^ ((arow >> 1) & 3)) << 3));
      #pragma unroll
      for (int nf = 0; nf < 2; ++nf)
        acc[mf][nf] = mfma16(ah, bh[nf], acc[mf][nf]);
    }
    __syncthreads();
  }

  for (int j = t; j < 2040; j += 512) cprm[j] = prm[j];

  float carry = 0.0f;

  #pragma unroll
  for (int c = 0; c < 4; ++c) {
    __syncthreads();
    if (wm == (c >> 1)) {
      #pragma unroll
      for (int d = 0; d < 4; ++d) {
        int mf = ((c & 1) << 2) + d;
        #pragma unroll
        for (int nf = 0; nf < 2; ++nf) {
          int bc = (wn << 5) + (nf << 4) + bl;
          #pragma unroll
          for (int r = 0; r < 4; ++r) {
            int lr = (d << 4) + (kh << 2) + r;
            cbuf[lr * CSTR + bc] = acc[mf][nf][r];
          }
        }
      }
    }
    __syncthreads();
    if (t < 128) {
      for (int lc = 0; lc < 64; lc += 4) {
        float v[4];
        #pragma unroll
        for (int u = 0; u < 4; ++u) v[u] = cbuf[(lc + u) * CSTR + t];
        #pragma unroll
        for (int u = 0; u < 4; ++u) {
          int l = (c << 6) + lc + u;
          carry = (l == 0) ? v[u] : combine_step(carry, v[u], cprm + ((l - 1) << 3));
        }
      }
    }
  }
  if (t < 128) out[b0 + t] = carry;
}

// ---------------- launch ----------------
extern "C" void kernel_launch(void* const* d_in, const int* in_sizes, int n_in,
                              void* d_out, int out_size, void* d_ws, size_t ws_size,
                              hipStream_t stream) {
  const float* x       = (const float*)d_in[0];   // (65536, 256)
  const float* logits  = (const float*)d_in[1];   // (256, 256)
  const float* weights = (const float*)d_in[2];   // (255, 2)
  const float* biases  = (const float*)d_in[3];   // (255,)
  float* out = (float*)d_out;                     // (65536, 1)

  char* ws = (char*)d_ws;
  int Btot = in_sizes[0] / 256;                   // 65536

  size_t Cbytes = (size_t)256 * (size_t)Btot * 4; // 64 MB
  size_t need   = Cbytes + 131072 + 8160;

  if (ws_size >= need && (Btot % 256) == 0) {
    // split path
    float* C   = (float*)ws;
    u16*   PTf = (u16*)(ws + Cbytes);
    float* prm = (float*)(ws + Cbytes + 131072);

    param_kernel<<<1, 256, 0, stream>>>(weights, biases, prm, 255);
    sinkhorn_kernel<<<1, 1024, 0, stream>>>(logits, PTf);
    gemm_store_kernel<<<Btot / 128, 512, 0, stream>>>(x, PTf, C, Btot);
    chain_kernel<<<Btot / 256, 256, 0, stream>>>(C, prm, out, Btot);
  } else {
    // fused fallback (round-6 structure)
    u16*   PTf = (u16*)ws;                        // 131072 B
    float* prm = (float*)(ws + 131072);           // 8160 B

    param_kernel<<<1, 256, 0, stream>>>(weights, biases, prm, 255);
    sinkhorn_kernel<<<1, 1024, 0, stream>>>(logits, PTf);
    gemm_chain_kernel<<<Btot / 128, 512, 0, stream>>>(x, PTf, prm, out);
  }
}